// Round 1
// 182.417 us; speedup vs baseline: 1.0190x; 1.0190x over previous
//
#include <hip/hip_runtime.h>
#include <math.h>

#define DIM 1024
#define DEPTH 7
#define PAR 8
#define N_NODES 255   // 2^(DEPTH+1) - 1
#define WIDTH 2040    // PAR * N_NODES
// f16-dot error sigma ~3e-4; 0.01 is ~30 sigma. (was 0.03 -> 3x fewer repairs)
#define MARGIN 0.01f

// lane that holds tree p's reduced logit after the fold network (bits 8/16/32)
#define REPLANE(p) ((((p) & 1) << 3) | ((((p) >> 1) & 1) << 4) | ((((p) >> 2) & 1) << 5))

typedef _Float16 half2v __attribute__((ext_vector_type(2)));

__device__ __forceinline__ half2v as_h2(unsigned int u) {
    union { unsigned int u; half2v h; } c; c.u = u; return c.h;
}
__device__ __forceinline__ unsigned int pack_h2(float a, float b) {
    union { half2v h; unsigned int u; } c;
    c.h = (half2v){(_Float16)a, (_Float16)b};   // v_cvt_f16_f32 is RTNE
    return c.u;
}

// f16 dot2 with fp32 accumulate; builtin if available, exact fallback otherwise
__device__ __forceinline__ float dot2h(unsigned int a, unsigned int b, float c) {
#if __has_builtin(__builtin_amdgcn_fdot2)
    return __builtin_amdgcn_fdot2(as_h2(a), as_h2(b), c, false);
#else
    half2v ha = as_h2(a), hb = as_h2(b);
    c = fmaf((float)ha.x, (float)hb.x, c);
    return fmaf((float)ha.y, (float)hb.y, c);
#endif
}

// fold two per-lane partial sums into one register, separating them by lane bit K.
__device__ __forceinline__ float foldK(float a, float b, int K) {
    const bool hi = (threadIdx.x & (unsigned)K) != 0;
    const float keep = hi ? b : a;
    const float send = hi ? a : b;
    return keep + __shfl_xor(send, K, 64);
}

// one tree's axpy: 8 f16 pairs -> fp32 acc via (float)h * a fma (v_fma_mix_f32 pattern)
#define PHASE_C_TREE(WLO, WHI, A) do {                                                      \
    const float a_ = (A); half2v h_;                                                        \
    h_ = as_h2((WLO).x); acc[0]  = fmaf((float)h_.x, a_, acc[0]);  acc[1]  = fmaf((float)h_.y, a_, acc[1]);  \
    h_ = as_h2((WLO).y); acc[2]  = fmaf((float)h_.x, a_, acc[2]);  acc[3]  = fmaf((float)h_.y, a_, acc[3]);  \
    h_ = as_h2((WLO).z); acc[4]  = fmaf((float)h_.x, a_, acc[4]);  acc[5]  = fmaf((float)h_.y, a_, acc[5]);  \
    h_ = as_h2((WLO).w); acc[6]  = fmaf((float)h_.x, a_, acc[6]);  acc[7]  = fmaf((float)h_.y, a_, acc[7]);  \
    h_ = as_h2((WHI).x); acc[8]  = fmaf((float)h_.x, a_, acc[8]);  acc[9]  = fmaf((float)h_.y, a_, acc[9]);  \
    h_ = as_h2((WHI).y); acc[10] = fmaf((float)h_.x, a_, acc[10]); acc[11] = fmaf((float)h_.y, a_, acc[11]); \
    h_ = as_h2((WHI).z); acc[12] = fmaf((float)h_.x, a_, acc[12]); acc[13] = fmaf((float)h_.y, a_, acc[13]); \
    h_ = as_h2((WHI).w); acc[14] = fmaf((float)h_.x, a_, acc[14]); acc[15] = fmaf((float)h_.y, a_, acc[15]); \
} while (0)

// ---------------------------------------------------------------------------
// Fused prep: blocks [0,512) transpose+convert W_out f32 [DIM][WIDTH] ->
// WoT f16 [WIDTH][DIM]; blocks [512,...) convert W_in f32 -> f16 packed.
// One launch instead of two.
// ---------------------------------------------------------------------------
#define TRANS_BLOCKS 512   // 32 (WIDTH/64 tiles) x 16 (DIM/64 tiles)

__global__ __launch_bounds__(256) void prep_kernel(
    const float* __restrict__ W_out,      // [DIM][WIDTH] f32
    const float* __restrict__ W_in,       // [WIDTH][DIM] f32
    unsigned short* __restrict__ WoT,     // [WIDTH][DIM] f16
    unsigned int* __restrict__ Wh)        // [WIDTH][DIM/2] f16-pair dwords
{
    __shared__ float tile[64][65];
    if (blockIdx.x < TRANS_BLOCKS) {
        const int w0 = (int)(blockIdx.x & 31) * 64;
        const int d0 = (int)(blockIdx.x >> 5) * 64;
        const int tid = (int)threadIdx.x;
        const int sub = tid & 15;
        const int grp = tid >> 4;

        #pragma unroll
        for (int pass = 0; pass < 4; ++pass) {
            const int dl = pass * 16 + grp;
            const int wl = sub * 4;
            const int w = w0 + wl;
            const int d = d0 + dl;
            float4 v = make_float4(0.f, 0.f, 0.f, 0.f);
            if (w + 3 < WIDTH) {
                v = *(const float4*)(W_out + (size_t)d * WIDTH + w);
            } else {
                float t0 = (w + 0 < WIDTH) ? W_out[(size_t)d * WIDTH + w + 0] : 0.f;
                float t1 = (w + 1 < WIDTH) ? W_out[(size_t)d * WIDTH + w + 1] : 0.f;
                float t2 = (w + 2 < WIDTH) ? W_out[(size_t)d * WIDTH + w + 2] : 0.f;
                float t3 = (w + 3 < WIDTH) ? W_out[(size_t)d * WIDTH + w + 3] : 0.f;
                v = make_float4(t0, t1, t2, t3);
            }
            tile[dl][wl + 0] = v.x; tile[dl][wl + 1] = v.y;
            tile[dl][wl + 2] = v.z; tile[dl][wl + 3] = v.w;
        }
        __syncthreads();
        #pragma unroll
        for (int pass = 0; pass < 4; ++pass) {
            const int wl = pass * 16 + grp;
            const int dl = sub * 4;
            const int w = w0 + wl;
            if (w < WIDTH) {
                uint2 pk;
                pk.x = pack_h2(tile[dl + 0][wl], tile[dl + 1][wl]);
                pk.y = pack_h2(tile[dl + 2][wl], tile[dl + 3][wl]);
                *(uint2*)(WoT + (size_t)w * DIM + d0 + dl) = pk;
            }
        }
    } else {
        const int n4 = WIDTH * DIM / 4;
        const int nthr = ((int)gridDim.x - TRANS_BLOCKS) * 256;
        for (int i = ((int)blockIdx.x - TRANS_BLOCKS) * 256 + (int)threadIdx.x;
             i < n4; i += nthr) {
            float4 v = ((const float4*)W_in)[i];
            uint2 pk;
            pk.x = pack_h2(v.x, v.y);
            pk.y = pack_h2(v.z, v.w);
            ((uint2*)Wh)[i] = pk;
        }
    }
}

// ---------------------------------------------------------------------------
// Main kernel: one wave per row. Per level: all gather addresses (Wh, WoT,
// bias) are computed up front and the loads issued early so WoT latency
// hides under the fold network instead of serializing after it.
// ---------------------------------------------------------------------------
__global__ __launch_bounds__(256) void fff_f16_kernel(
    const float* __restrict__ x,            // [B, DIM] f32
    const float* __restrict__ W_in,         // [WIDTH, DIM] f32 (repair only)
    const float* __restrict__ b_in,         // [WIDTH] f32
    const unsigned int* __restrict__ Wh,    // f16 W_in  [WIDTH][DIM/2] dwords
    const unsigned short* __restrict__ WoT, // f16 W_out^T [WIDTH][DIM]
    float* __restrict__ out,                // [B, DIM] f32
    int B)
{
    const int wave = (int)((blockIdx.x * blockDim.x + threadIdx.x) >> 6);
    const int lane = (int)(threadIdx.x & 63);
    if (wave >= B) return;

    const float* xr = x + (size_t)wave * DIM;
    unsigned int xp[8];
    {
        float4 a0 = *(const float4*)(xr + lane * 8 + 0);
        float4 a1 = *(const float4*)(xr + lane * 8 + 4);
        float4 a2 = *(const float4*)(xr + 512 + lane * 8 + 0);
        float4 a3 = *(const float4*)(xr + 512 + lane * 8 + 4);
        xp[0] = pack_h2(a0.x, a0.y);
        xp[1] = pack_h2(a0.z, a0.w);
        xp[2] = pack_h2(a1.x, a1.y);
        xp[3] = pack_h2(a1.z, a1.w);
        xp[4] = pack_h2(a2.x, a2.y);
        xp[5] = pack_h2(a2.z, a2.w);
        xp[6] = pack_h2(a3.x, a3.y);
        xp[7] = pack_h2(a3.z, a3.w);
    }

    float acc[16];
    #pragma unroll
    for (int i = 0; i < 16; ++i) acc[i] = 0.f;

    unsigned long long nodes = 0ULL;   // 8 x u8 node indices (all < 255)
    const int myp = ((lane >> 3) & 1) | (((lane >> 4) & 1) << 1) | (((lane >> 5) & 1) << 2);

    #pragma unroll 1
    for (int d = 0; d <= DEPTH; ++d) {
        int gidx[PAR];
        #pragma unroll
        for (int p = 0; p < PAR; ++p) {
            const int np = (int)((nodes >> (8 * p)) & 0xffULL);
            gidx[p] = p * N_NODES + np;
        }

        // bias row index depends only on gidx + lane bits -> issue the gather early
        const int ga = (lane & 8) ? gidx[1] : gidx[0];
        const int gb = (lane & 8) ? gidx[3] : gidx[2];
        const int gc = (lane & 8) ? gidx[5] : gidx[4];
        const int gd = (lane & 8) ? gidx[7] : gidx[6];
        const int ge = (lane & 16) ? gb : ga;
        const int gf = (lane & 16) ? gd : gc;
        const int gmine = (lane & 32) ? gf : ge;
        const float bias = b_in[gmine];

        // Phase A loads: 16 x dwordx4 (f16 W_in rows)
        uint4 ua[PAR], ub[PAR];
        #pragma unroll
        for (int p = 0; p < PAR; ++p) {
            const unsigned int* wr = Wh + (size_t)gidx[p] * (DIM / 2);
            ua[p] = *(const uint4*)(wr + lane * 4);
            ub[p] = *(const uint4*)(wr + 256 + lane * 4);
        }

        // Phase A dots: one v_dot2_f32_f16 per dword
        float partial[PAR];
        #pragma unroll
        for (int p = 0; p < PAR; ++p) {
            float s = 0.f;
            s = dot2h(xp[0], ua[p].x, s);
            s = dot2h(xp[1], ua[p].y, s);
            s = dot2h(xp[2], ua[p].z, s);
            s = dot2h(xp[3], ua[p].w, s);
            s = dot2h(xp[4], ub[p].x, s);
            s = dot2h(xp[5], ub[p].y, s);
            s = dot2h(xp[6], ub[p].z, s);
            s = dot2h(xp[7], ub[p].w, s);
            partial[p] = s;
        }

        // Phase C batch-A prefetch (trees 0-3): latency hides under fold+repair+silu
        uint4 wva[4], wvb[4];
        #pragma unroll
        for (int p = 0; p < 4; ++p) {
            const unsigned short* wo = WoT + (size_t)gidx[p] * DIM;
            wva[p] = *(const uint4*)(wo + lane * 8);
            wvb[p] = *(const uint4*)(wo + 512 + lane * 8);
        }

        // Phase B: fold network over lane bits {8,16,32}, butterfly over {1,2,4}
        const float c01 = foldK(partial[0], partial[1], 8);
        const float c23 = foldK(partial[2], partial[3], 8);
        const float c45 = foldK(partial[4], partial[5], 8);
        const float c67 = foldK(partial[6], partial[7], 8);
        const float d0f = foldK(c01, c23, 16);
        const float d1f = foldK(c45, c67, 16);
        float e = foldK(d0f, d1f, 32);
        e += __shfl_xor(e, 1, 64);
        e += __shfl_xor(e, 2, 64);
        e += __shfl_xor(e, 4, 64);
        float my = e + bias;

        // Repair: near-zero logits recomputed in fp32 (decisions must match numpy)
        if (d < DEPTH) {
            const unsigned long long bal = __ballot(fabsf(my) < MARGIN);
            unsigned rm = 0;
            #pragma unroll
            for (int p = 0; p < PAR; ++p)
                rm |= ((unsigned)((bal >> REPLANE(p)) & 1ULL)) << p;
            if (rm) {
                const float4 fa = *(const float4*)(xr + lane * 8 + 0);
                const float4 fb = *(const float4*)(xr + lane * 8 + 4);
                const float4 fc = *(const float4*)(xr + 512 + lane * 8 + 0);
                const float4 fd = *(const float4*)(xr + 512 + lane * 8 + 4);
                while (rm) {
                    const int p = __builtin_ctz(rm); rm &= (rm - 1u);
                    const int gi = gidx[p];
                    const float* wr = W_in + (size_t)gi * DIM;
                    const float4 wa = *(const float4*)(wr + lane * 8 + 0);
                    const float4 wb = *(const float4*)(wr + lane * 8 + 4);
                    const float4 wc = *(const float4*)(wr + 512 + lane * 8 + 0);
                    const float4 wd = *(const float4*)(wr + 512 + lane * 8 + 4);
                    float s = 0.f;
                    s = fmaf(fa.x, wa.x, s); s = fmaf(fa.y, wa.y, s);
                    s = fmaf(fa.z, wa.z, s); s = fmaf(fa.w, wa.w, s);
                    s = fmaf(fb.x, wb.x, s); s = fmaf(fb.y, wb.y, s);
                    s = fmaf(fb.z, wb.z, s); s = fmaf(fb.w, wb.w, s);
                    s = fmaf(fc.x, wc.x, s); s = fmaf(fc.y, wc.y, s);
                    s = fmaf(fc.z, wc.z, s); s = fmaf(fc.w, wc.w, s);
                    s = fmaf(fd.x, wd.x, s); s = fmaf(fd.y, wd.y, s);
                    s = fmaf(fd.z, wd.z, s); s = fmaf(fd.w, wd.w, s);
                    #pragma unroll
                    for (int off = 32; off >= 1; off >>= 1)
                        s += __shfl_xor(s, off, 64);
                    const float lf = s + b_in[gi];
                    my = (myp == p) ? lf : my;
                }
            }
        }

        // per-lane silu (8 trees in parallel), decisions via one ballot
        const float act_mine = my / (1.0f + __expf(-my));
        const unsigned long long pos = __ballot(my > 0.0f);

        float act[PAR];
        #pragma unroll
        for (int p = 0; p < PAR; ++p)
            act[p] = __shfl(act_mine, REPLANE(p), 64);

        // Phase C batch-B prefetch (trees 4-7): latency hides under batch-A fmas
        uint4 wvc[4], wvd[4];
        #pragma unroll
        for (int p = 0; p < 4; ++p) {
            const unsigned short* wo = WoT + (size_t)gidx[4 + p] * DIM;
            wvc[p] = *(const uint4*)(wo + lane * 8);
            wvd[p] = *(const uint4*)(wo + 512 + lane * 8);
        }

        // Phase C: f16 axpy into fp32 acc (v_fma_mix pattern)
        #pragma unroll
        for (int p = 0; p < 4; ++p) PHASE_C_TREE(wva[p], wvb[p], act[p]);
        #pragma unroll
        for (int p = 0; p < 4; ++p) PHASE_C_TREE(wvc[p], wvd[p], act[4 + p]);

        if (d < DEPTH) {
            #pragma unroll
            for (int p = 0; p < PAR; ++p) {
                const int np = (int)((nodes >> (8 * p)) & 0xffULL);
                const unsigned long long nn = (unsigned long long)
                    (2 * np + 1 + (int)((pos >> REPLANE(p)) & 1ULL));
                nodes = (nodes & ~(0xffULL << (8 * p))) | (nn << (8 * p));
            }
        }
    }

    float* orow = out + (size_t)wave * DIM;
    *(float4*)(orow + lane * 8 + 0)       = make_float4(acc[0],  acc[1],  acc[2],  acc[3]);
    *(float4*)(orow + lane * 8 + 4)       = make_float4(acc[4],  acc[5],  acc[6],  acc[7]);
    *(float4*)(orow + 512 + lane * 8 + 0) = make_float4(acc[8],  acc[9],  acc[10], acc[11]);
    *(float4*)(orow + 512 + lane * 8 + 4) = make_float4(acc[12], acc[13], acc[14], acc[15]);
}

// ---------------------------------------------------------------------------
// Fallback (no workspace): fp32 gather both stages. Correct but slow.
// ---------------------------------------------------------------------------
__global__ __launch_bounds__(256) void fff_fallback_kernel(
    const float* __restrict__ x, const float* __restrict__ W_in,
    const float* __restrict__ b_in, const float* __restrict__ W_out,
    float* __restrict__ out, int B)
{
    const int wave = (int)((blockIdx.x * blockDim.x + threadIdx.x) >> 6);
    const int lane = (int)(threadIdx.x & 63);
    if (wave >= B) return;

    const float* xr = x + (size_t)wave * DIM;
    float4 x4[4];
    x4[0] = *(const float4*)(xr + lane * 8 + 0);
    x4[1] = *(const float4*)(xr + lane * 8 + 4);
    x4[2] = *(const float4*)(xr + 512 + lane * 8 + 0);
    x4[3] = *(const float4*)(xr + 512 + lane * 8 + 4);

    float acc[16];
    #pragma unroll
    for (int i = 0; i < 16; ++i) acc[i] = 0.f;
    int node[PAR];
    #pragma unroll
    for (int p = 0; p < PAR; ++p) node[p] = 0;

    for (int d = 0; d <= DEPTH; ++d) {
        #pragma unroll
        for (int p = 0; p < PAR; ++p) {
            const int gidx = p * N_NODES + node[p];
            const float* wr = W_in + (size_t)gidx * DIM;
            const float4 wa = *(const float4*)(wr + lane * 8 + 0);
            const float4 wb = *(const float4*)(wr + lane * 8 + 4);
            const float4 wc = *(const float4*)(wr + 512 + lane * 8 + 0);
            const float4 wd = *(const float4*)(wr + 512 + lane * 8 + 4);
            float s = 0.f;
            s = fmaf(x4[0].x, wa.x, s); s = fmaf(x4[0].y, wa.y, s);
            s = fmaf(x4[0].z, wa.z, s); s = fmaf(x4[0].w, wa.w, s);
            s = fmaf(x4[1].x, wb.x, s); s = fmaf(x4[1].y, wb.y, s);
            s = fmaf(x4[1].z, wb.z, s); s = fmaf(x4[1].w, wb.w, s);
            s = fmaf(x4[2].x, wc.x, s); s = fmaf(x4[2].y, wc.y, s);
            s = fmaf(x4[2].z, wc.z, s); s = fmaf(x4[2].w, wc.w, s);
            s = fmaf(x4[3].x, wd.x, s); s = fmaf(x4[3].y, wd.y, s);
            s = fmaf(x4[3].z, wd.z, s); s = fmaf(x4[3].w, wd.w, s);
            #pragma unroll
            for (int off = 32; off >= 1; off >>= 1)
                s += __shfl_xor(s, off, 64);
            const float logit = s + b_in[gidx];
            const float act = logit / (1.0f + __expf(-logit));
            #pragma unroll
            for (int k = 0; k < 2; ++k) {
                #pragma unroll
                for (int j = 0; j < 8; ++j) {
                    const int e = k * 512 + lane * 8 + j;
                    acc[k * 8 + j] = fmaf(act, W_out[(size_t)e * WIDTH + gidx], acc[k * 8 + j]);
                }
            }
            node[p] = 2 * node[p] + 1 + ((logit > 0.0f) ? 1 : 0);
        }
    }

    float* orow = out + (size_t)wave * DIM;
    *(float4*)(orow + lane * 8 + 0)       = make_float4(acc[0],  acc[1],  acc[2],  acc[3]);
    *(float4*)(orow + lane * 8 + 4)       = make_float4(acc[4],  acc[5],  acc[6],  acc[7]);
    *(float4*)(orow + 512 + lane * 8 + 0) = make_float4(acc[8],  acc[9],  acc[10], acc[11]);
    *(float4*)(orow + 512 + lane * 8 + 4) = make_float4(acc[12], acc[13], acc[14], acc[15]);
}

extern "C" void kernel_launch(void* const* d_in, const int* in_sizes, int n_in,
                              void* d_out, int out_size, void* d_ws, size_t ws_size,
                              hipStream_t stream) {
    const float* oldx  = (const float*)d_in[0];
    const float* W_in  = (const float*)d_in[1];
    const float* b_in  = (const float*)d_in[2];
    const float* W_out = (const float*)d_in[3];
    float* out = (float*)d_out;

    const int B = in_sizes[0] / DIM;   // 8192 rows

    const size_t half = (size_t)WIDTH * DIM * sizeof(unsigned short);  // 4.18 MB
    const bool use_lp = (ws_size >= 2 * half) && (d_ws != nullptr);

    const int blocks = (B + 3) / 4;    // 4 waves (256 threads) per block

    if (use_lp) {
        unsigned short* WoT = (unsigned short*)d_ws;
        unsigned int*   Wh  = (unsigned int*)((char*)d_ws + half);
        prep_kernel<<<TRANS_BLOCKS + 1024, 256, 0, stream>>>(W_out, W_in, WoT, Wh);
        fff_f16_kernel<<<blocks, 256, 0, stream>>>(oldx, W_in, b_in, Wh, WoT, out, B);
    } else {
        fff_fallback_kernel<<<blocks, 256, 0, stream>>>(oldx, W_in, b_in, W_out, out, B);
    }
}